// Round 9
// baseline (439.831 us; speedup 1.0000x reference)
//
#include <hip/hip_runtime.h>
#include <stdint.h>

typedef __bf16 bf16_t;
typedef __bf16 bf16x8 __attribute__((ext_vector_type(8)));
typedef __bf16 bf16x4 __attribute__((ext_vector_type(4)));
typedef float  f32x4  __attribute__((ext_vector_type(4)));

static constexpr int S  = 4096;
static constexpr int D  = 2048;
static constexpr int H  = 16;
static constexpr int DH = 128;

__device__ __forceinline__ bf16x8 ld8(const bf16_t* p) { return *(const bf16x8*)p; }
__device__ __forceinline__ bf16x4 ld4(const bf16_t* p) { return *(const bf16x4*)p; }
__device__ __forceinline__ bf16x8 ld8c(const float* p) {
  const f32x4 a = *(const f32x4*)p;
  const f32x4 b = *(const f32x4*)(p + 4);
  bf16x8 r;
  r[0] = (bf16_t)a[0]; r[1] = (bf16_t)a[1]; r[2] = (bf16_t)a[2]; r[3] = (bf16_t)a[3];
  r[4] = (bf16_t)b[0]; r[5] = (bf16_t)b[1]; r[6] = (bf16_t)b[2]; r[7] = (bf16_t)b[3];
  return r;
}

// async global->LDS, 16B/lane; LDS dest = wave-uniform base + lane*16 (m97/m104)
__device__ __forceinline__ void async_ld16(const bf16_t* g, bf16_t* lds) {
  __builtin_amdgcn_global_load_lds(
      (const __attribute__((address_space(1))) uint32_t*)g,
      (__attribute__((address_space(3))) uint32_t*)lds, 16, 0, 0);
}

// ---------------------------------------------------------------------------
// f32 -> bf16 convert: 6 slices of 4,194,304 elems (x = slices 0,1; weights 2-5)
// ---------------------------------------------------------------------------
__global__ __launch_bounds__(256) void cvt_kernel(
    const float* __restrict__ x,  const float* __restrict__ wq,
    const float* __restrict__ wk, const float* __restrict__ wv,
    const float* __restrict__ wo,
    bf16_t* __restrict__ xb,  bf16_t* __restrict__ wqb,
    bf16_t* __restrict__ wkb, bf16_t* __restrict__ wvb,
    bf16_t* __restrict__ wob) {
  const int z = blockIdx.z;
  const float* src; bf16_t* dst; size_t off = 0;
  if      (z == 0) { src = x;  dst = xb;  off = 0; }
  else if (z == 1) { src = x;  dst = xb;  off = 4194304; }
  else if (z == 2) { src = wq; dst = wqb; }
  else if (z == 3) { src = wk; dst = wkb; }
  else if (z == 4) { src = wv; dst = wvb; }
  else             { src = wo; dst = wob; }
  const size_t i = off + ((size_t)blockIdx.x * 256 + threadIdx.x) * 8;
  *(bf16x8*)(dst + i) = ld8c(src + i);
}

// ---------------------------------------------------------------------------
// bf16 NT GEMM, async global->LDS staging (m97). C = A[M,K] * W[N,K]^T.
// 128x128 tile, BK=32, 256 threads. TR=true writes C^T ([N][S]) for V^T.
// ---------------------------------------------------------------------------
template <typename TC, bool TR>
__device__ __forceinline__ void gemm_async(const bf16_t* __restrict__ A,
                                           const bf16_t* __restrict__ W,
                                           TC* __restrict__ C) {
  constexpr int K  = D;
  constexpr int BK = 32;
  __shared__ __align__(16) bf16_t Ash[128 * BK];
  __shared__ __align__(16) bf16_t Bsh[128 * BK];
  const int tid = threadIdx.x;
  const int w = tid >> 6, lane = tid & 63;
  const int c = lane & 15, g = lane >> 4;
  const int wm = w >> 1, wn = w & 1;
  const int rowBase = blockIdx.y * 128;
  const int colBase = blockIdx.x * 128;

  f32x4 acc[4][4] = {};

  for (int k0 = 0; k0 < K; k0 += BK) {
    __syncthreads();
    #pragma unroll
    for (int r = 0; r < 2; ++r) {
      const int cid = r * 256 + tid;
      const int row = cid >> 2, q = cid & 3;
      async_ld16(A + (size_t)(rowBase + row) * K + k0 + q * 8,
                 Ash + r * 2048 + w * 512);
      async_ld16(W + (size_t)(colBase + row) * K + k0 + q * 8,
                 Bsh + r * 2048 + w * 512);
    }
    __syncthreads();

    bf16x8 af[4], bf[4];
    #pragma unroll
    for (int i = 0; i < 4; ++i) af[i] = ld8(Ash + (wm * 64 + i * 16 + c) * BK + g * 8);
    #pragma unroll
    for (int j = 0; j < 4; ++j) bf[j] = ld8(Bsh + (wn * 64 + j * 16 + c) * BK + g * 8);
    #pragma unroll
    for (int i = 0; i < 4; ++i)
      #pragma unroll
      for (int j = 0; j < 4; ++j)
        acc[i][j] = __builtin_amdgcn_mfma_f32_16x16x32_bf16(af[i], bf[j], acc[i][j], 0, 0, 0);
  }

  // C/D layout: col=lane&15, row=(lane>>4)*4+reg (m89/m91)
  #pragma unroll
  for (int i = 0; i < 4; ++i)
    #pragma unroll
    for (int j = 0; j < 4; ++j) {
      if (TR) {
        const int col  = colBase + wn * 64 + j * 16 + c;
        const int row0 = rowBase + wm * 64 + i * 16 + g * 4;
        bf16x4 v;
        #pragma unroll
        for (int r = 0; r < 4; ++r) v[r] = (bf16_t)acc[i][j][r];
        *(bf16x4*)((bf16_t*)C + (size_t)col * S + row0) = v;
      } else {
        #pragma unroll
        for (int r = 0; r < 4; ++r) {
          const int row = rowBase + wm * 64 + i * 16 + g * 4 + r;
          const int col = colBase + wn * 64 + j * 16 + c;
          C[(size_t)row * D + col] = (TC)acc[i][j][r];
        }
      }
    }
}

__global__ __launch_bounds__(256) void qkv_gemm_bf16(
    const bf16_t* __restrict__ X,
    const bf16_t* __restrict__ Wq, const bf16_t* __restrict__ Wk,
    const bf16_t* __restrict__ Wv,
    bf16_t* __restrict__ Qo, bf16_t* __restrict__ Ko, bf16_t* __restrict__ VTo) {
  if (blockIdx.z == 0)      gemm_async<bf16_t, false>(X, Wq, Qo);
  else if (blockIdx.z == 1) gemm_async<bf16_t, false>(X, Wk, Ko);
  else                      gemm_async<bf16_t, true >(X, Wv, VTo);  // V^T
}

__global__ __launch_bounds__(256) void out_gemm_bf16(
    const bf16_t* __restrict__ A, const bf16_t* __restrict__ W,
    float* __restrict__ C) {
  gemm_async<float, false>(A, W, C);
}

// ---------------------------------------------------------------------------
// Causal flash attention, 512 threads = 8 waves, work stealing, 32-row waves.
// r9 change vs r8: the P LDS round-trip is DELETED via a k-slot remap.
// MFMA contracts over k with any bijective k-slot<->key map as long as A and
// B agree. Choose sigma(g,j) = (j<4 ? g*4+j : 16+g*4+(j-4)): the PV
// A-fragment is then exactly the lane's own post-exp2 registers (lane (c,g)
// holds P[keys {g*4+r, 16+g*4+r}][qrow c] after swapped QK^T) -> zero LDS,
// zero cross-lane exchange. The B-side (V) reads with the same map: two
// ds_read_b64 per d-fragment at granules (wk*8+{0,4}+g)^((dl&7)<<1); this
// 8-B-granule XOR preserves 16-B chunk pairs, so the global_load_lds source
// swizzle is UNCHANGED. Bank math: lanes c,c+8 alias (2-way = free).
// Removes per wave-tile: 4 ds_write_b64 + 2 ds_read_b128 + the
// write->lgkmcnt->read serial dependency (the only intra-tile LDS chain).
// Psh freed: LDS = 72 KB (merge scratch ceiling) + item_s -> 74240 B request,
// 2x74240 < 160 KiB -> 2 blocks/CU kept.
//
// Wave (wq 0..3, wk 0..1) = q-rows [t*128+wq*32,+32) x keys [kt*64+wk*32,+32).
// Item = (128-row q-tile t, head h): 512 items on 384 slots (1.33:1 steal
// slack). Heavy-first: t = 31 - (it>>4). Fixed softmax shift m=0 (wk-half
// partials exactly additive); global_load_lds double-buffer, incremental src
// pointers, ONE __syncthreads per tile; source-chunk XOR swizzle (rule #21).
//   KB[2][64 keys][128 dh]   16 KB x2
//   VB[2][128 dh][64 keys]   16 KB x2
//   merge scratch 72 KB (aliases staging; ordered by loop barriers)
// ---------------------------------------------------------------------------
__global__ __launch_bounds__(512, 2) void attn_kernel(
    const bf16_t* __restrict__ Q, const bf16_t* __restrict__ Kb,
    const bf16_t* __restrict__ VTg, bf16_t* __restrict__ O,
    const int* __restrict__ causal_p, int* __restrict__ ctr) {
  __shared__ __align__(16) bf16_t smem[36864];       // 72 KB (merge ceiling)
  bf16_t* const KB0 = smem;                          // [2][8192]
  bf16_t* const VB0 = smem + 16384;                  // [2][8192]
  __shared__ int item_s;

  const int tid = threadIdx.x, w = tid >> 6, lane = tid & 63;
  const int c = lane & 15, g = lane >> 4;
  const int wq = w >> 1, wk = w & 1;
  const int causal = causal_p[0];
  constexpr float QS = 0.08838834764831845f * 1.4426950408889634f; // sm*log2e

  // staging coords: cid = r*512+tid enumerates 16B chunks of a 16KB tile.
  // K tile [kn 64][dh 128]: row=cid>>4, chunk=cid&15 ; source chunk ^= row&7.
  // V tile [d 128][key 64]: row=cid>>3, chunk=cid&7  ; source chunk ^= row&7.
  int knA[2], qK8[2], dVA[2], qV8[2];
  #pragma unroll
  for (int r = 0; r < 2; ++r) {
    const int cid = r * 512 + tid;
    knA[r] = cid >> 4; qK8[r] = (((cid & 15) ^ (knA[r] & 7)) << 3);
    dVA[r] = cid >> 3; qV8[r] = (((cid & 7) ^ (dVA[r] & 7)) << 3);
  }

  while (true) {
    if (tid == 0) item_s = atomicAdd(ctr, 1);
    __syncthreads();                    // publish item_s; prev epilogue done
    const int it = item_s;
    if (it >= 512) break;
    const int t = causal ? (31 - (it >> 4)) : (it >> 4);     // heavy-first
    const int h = it & 15;
    const int qrow0 = t * 128 + wq * 32;
    const int ktiles = causal ? (2 * t + 2) : (S / 64);

    // incremental staging source pointers (advance by fixed strides/tile)
    const bf16_t* kSrc[2];
    const bf16_t* vSrc[2];
    #pragma unroll
    for (int r = 0; r < 2; ++r) {
      kSrc[r] = Kb + (size_t)knA[r] * D + h * DH + qK8[r];
      vSrc[r] = VTg + (size_t)(h * DH + dVA[r]) * S + qV8[r];
    }
    // prologue: stage tile 0 into buffer 0 (flies under Q-frag loads below)
    #pragma unroll
    for (int r = 0; r < 2; ++r) {
      async_ld16(kSrc[r], KB0 + r * 4096 + w * 512);
      async_ld16(vSrc[r], VB0 + r * 4096 + w * 512);
      kSrc[r] += (size_t)64 * D;
      vSrc[r] += 64;
    }

    // Q fragments (B operand: n=lane&15=q-row in i-group, k=(lane>>4)*8+j)
    bf16x8 qf[2][4];
    #pragma unroll
    for (int i = 0; i < 2; ++i)
      #pragma unroll
      for (int kf = 0; kf < 4; ++kf) {
        const bf16x8 raw = ld8(Q + (size_t)(qrow0 + i * 16 + c) * D + h * DH + kf * 32 + g * 8);
        bf16x8 sc;
        #pragma unroll
        for (int e = 0; e < 8; ++e) sc[e] = (bf16_t)((float)raw[e] * QS);
        qf[i][kf] = sc;
      }

    f32x4 o_acc[2][8] = {};
    float psum[2] = {0.0f, 0.0f};

    __syncthreads();   // tile 0 landed (vmcnt(0) drained at barrier)

    int cur = 0;
    for (int kt = 0; kt < ktiles; ++kt) {
      // issue next tile's loads into alt buffer (fly during compute)
      if (kt + 1 < ktiles) {
        const int alt = cur ^ 1;
        #pragma unroll
        for (int r = 0; r < 2; ++r) {
          async_ld16(kSrc[r], KB0 + alt * 8192 + r * 4096 + w * 512);
          async_ld16(vSrc[r], VB0 + alt * 8192 + r * 4096 + w * 512);
          kSrc[r] += (size_t)64 * D;
          vSrc[r] += 64;
        }
      }

      const bf16_t* const KB = KB0 + cur * 8192;
      const bf16_t* const VB = VB0 + cur * 8192;
      const int kb = kt * 64 + wk * 32;          // this wave's key base

      // fully-masked key-half for this wave's 32 rows?
      const bool active = !causal || (kb <= qrow0 + 31);
      if (active) {
        __builtin_amdgcn_s_setprio(1);
        // --- S^T = K Q^T (swapped): D col=c=q-row, regs = keys nf*16+g*4+r ---
        bf16x4 pq[2][2];   // [i][nf] : P for keys nf*16+g*4+{0..3}, qrow c
        #pragma unroll
        for (int nf = 0; nf < 2; ++nf) {
          const int rr = wk * 32 + nf * 16 + c;   // key row in tile (A m-idx)
          bf16x8 kk[4];
          #pragma unroll
          for (int kf = 0; kf < 4; ++kf)
            kk[kf] = ld8(KB + rr * 128 + ((((kf << 2) + g) ^ (rr & 7)) << 3));
          #pragma unroll
          for (int i = 0; i < 2; ++i) {
            f32x4 s = {};
            #pragma unroll
            for (int kf = 0; kf < 4; ++kf)
              s = __builtin_amdgcn_mfma_f32_16x16x32_bf16(kk[kf], qf[i][kf], s, 0, 0, 0);
            // causal mask: key = kb+nf*16+g*4+r, qrow = qrow0+i*16+c
            if (causal && (kb + nf * 16 + 15 > qrow0 + i * 16)) {
              #pragma unroll
              for (int r_ = 0; r_ < 4; ++r_)
                if (kb + nf * 16 + g * 4 + r_ > qrow0 + i * 16 + c) s[r_] = -1e30f;
            }
            // P = exp2(S) (fixed m=0), kept in registers
            #pragma unroll
            for (int r_ = 0; r_ < 4; ++r_) {
              const float pv = exp2f(s[r_]);
              psum[i] += pv;
              pq[i][nf][r_] = (bf16_t)pv;
            }
          }
        }

        // --- PV A-fragments from registers (k-slot map sigma: j<4 -> nf=0
        //     keys g*4+j ; j>=4 -> nf=1 keys 16+g*4+(j-4)) ---
        bf16x8 pf[2];
        #pragma unroll
        for (int i = 0; i < 2; ++i) {
          pf[i][0] = pq[i][0][0]; pf[i][1] = pq[i][0][1];
          pf[i][2] = pq[i][0][2]; pf[i][3] = pq[i][0][3];
          pf[i][4] = pq[i][1][0]; pf[i][5] = pq[i][1][1];
          pf[i][6] = pq[i][1][2]; pf[i][7] = pq[i][1][3];
        }

        // --- O += P V : V B-frags via 2x ds_read_b64 with the SAME k map ---
        #pragma unroll
        for (int nfd = 0; nfd < 8; ++nfd) {
          const int dl = nfd * 16 + c;
          const int sw = (dl & 7) << 1;           // 8-B-granule XOR swizzle
          const bf16x4 v0 = ld4(VB + dl * 64 + ((((wk << 3) + g) ^ sw) << 2));
          const bf16x4 v1 = ld4(VB + dl * 64 + ((((wk << 3) + 4 + g) ^ sw) << 2));
          bf16x8 vf;
          vf[0] = v0[0]; vf[1] = v0[1]; vf[2] = v0[2]; vf[3] = v0[3];
          vf[4] = v1[0]; vf[5] = v1[1]; vf[6] = v1[2]; vf[7] = v1[3];
          o_acc[0][nfd] = __builtin_amdgcn_mfma_f32_16x16x32_bf16(pf[0], vf, o_acc[0][nfd], 0, 0, 0);
          o_acc[1][nfd] = __builtin_amdgcn_mfma_f32_16x16x32_bf16(pf[1], vf, o_acc[1][nfd], 0, 0, 0);
        }
        __builtin_amdgcn_s_setprio(0);
      }

      __syncthreads();   // next tile staged; prev reads done; swap
      cur ^= 1;
    }

    // --- merge wk=1 -> wk=0 via LDS scratch (4 wq x 64 lanes x 72 f32 =
    //     73728 B = smem exactly; loop-final barrier ordered buffer reuse) ---
    float* const slot = (float*)smem + (size_t)(wq * 64 + lane) * 72;
    if (wk == 1) {
      #pragma unroll
      for (int i = 0; i < 2; ++i)
        #pragma unroll
        for (int nf = 0; nf < 8; ++nf)
          *(f32x4*)(slot + (i * 8 + nf) * 4) = o_acc[i][nf];
      slot[64] = psum[0];
      slot[65] = psum[1];
    }
    __syncthreads();
    if (wk == 0) {
      #pragma unroll
      for (int i = 0; i < 2; ++i)
        #pragma unroll
        for (int nf = 0; nf < 8; ++nf)
          o_acc[i][nf] += *(const f32x4*)(slot + (i * 8 + nf) * 4);
      psum[0] += slot[64];
      psum[1] += slot[65];
      // row-sum: psum[i] is per (q-row c, g) partial; reduce over g-groups
      #pragma unroll
      for (int i = 0; i < 2; ++i) {
        float v = psum[i];
        v += __shfl_xor(v, 16); v += __shfl_xor(v, 32);
        // normalize + write: o_acc[i][nf][r] is row qrow0+i*16+g*4+r, col nf*16+c
        #pragma unroll
        for (int r_ = 0; r_ < 4; ++r_) {
          const float inv = 1.0f / __shfl(v, g * 4 + r_, 64);
          const int row = qrow0 + i * 16 + g * 4 + r_;
          #pragma unroll
          for (int nf = 0; nf < 8; ++nf)
            O[(size_t)row * D + h * DH + nf * 16 + c] = (bf16_t)(o_acc[i][nf][r_] * inv);
        }
      }
    }
  }
}

// ---------------------------------------------------------------------------
extern "C" void kernel_launch(void* const* d_in, const int* in_sizes, int n_in,
                              void* d_out, int out_size, void* d_ws, size_t ws_size,
                              hipStream_t stream) {
  const float* x  = (const float*)d_in[0];
  const float* wq = (const float*)d_in[1];
  const float* wk = (const float*)d_in[2];
  const float* wv = (const float*)d_in[3];
  const float* wo = (const float*)d_in[4];
  const int* causal = (const int*)d_in[5];
  float* out = (float*)d_out;

  bf16_t* Qb  = (bf16_t*)d_ws;           // [S][D]
  bf16_t* Kb  = Qb + (size_t)S * D;      // [S][D]
  bf16_t* VTb = Kb + (size_t)S * D;      // V^T: [D][S]
  bf16_t* Ob  = VTb + (size_t)S * D;     // [S][D]
  bf16_t* xb  = Ob + (size_t)S * D;
  bf16_t* wqb = xb + (size_t)S * D;
  bf16_t* wkb = wqb + (size_t)D * D;
  bf16_t* wvb = wkb + (size_t)D * D;
  bf16_t* wob = wvb + (size_t)D * D;
  int*    ctr = (int*)(wob + (size_t)D * D);

  // zero the attention work-queue counter (graph-capturable async memset)
  hipMemsetAsync(ctr, 0, sizeof(int), stream);

  dim3 blk(256);
  cvt_kernel<<<dim3(2048, 1, 6), blk, 0, stream>>>(x, wq, wk, wv, wo,
                                                   xb, wqb, wkb, wvb, wob);
  qkv_gemm_bf16<<<dim3(D / 128, S / 128, 3), blk, 0, stream>>>(xb, wqb, wkb, wvb,
                                                               Qb, Kb, VTb);
  attn_kernel<<<dim3(384), dim3(512), 0, stream>>>(Qb, Kb, VTb, Ob, causal, ctr);
  out_gemm_bf16<<<dim3(D / 128, S / 128), blk, 0, stream>>>(Ob, wob, out);
}

// Round 10
// 407.068 us; speedup vs baseline: 1.0805x; 1.0805x over previous
//
#include <hip/hip_runtime.h>
#include <stdint.h>

typedef __bf16 bf16_t;
typedef __bf16 bf16x8 __attribute__((ext_vector_type(8)));
typedef __bf16 bf16x4 __attribute__((ext_vector_type(4)));
typedef float  f32x4  __attribute__((ext_vector_type(4)));

static constexpr int S  = 4096;
static constexpr int D  = 2048;
static constexpr int H  = 16;
static constexpr int DH = 128;

__device__ __forceinline__ bf16x8 ld8(const bf16_t* p) { return *(const bf16x8*)p; }
__device__ __forceinline__ bf16x8 ld8c(const float* p) {
  const f32x4 a = *(const f32x4*)p;
  const f32x4 b = *(const f32x4*)(p + 4);
  bf16x8 r;
  r[0] = (bf16_t)a[0]; r[1] = (bf16_t)a[1]; r[2] = (bf16_t)a[2]; r[3] = (bf16_t)a[3];
  r[4] = (bf16_t)b[0]; r[5] = (bf16_t)b[1]; r[6] = (bf16_t)b[2]; r[7] = (bf16_t)b[3];
  return r;
}

// async global->LDS, 16B/lane; LDS dest = wave-uniform base + lane*16 (m97/m104)
__device__ __forceinline__ void async_ld16(const bf16_t* g, bf16_t* lds) {
  __builtin_amdgcn_global_load_lds(
      (const __attribute__((address_space(1))) uint32_t*)g,
      (__attribute__((address_space(3))) uint32_t*)lds, 16, 0, 0);
}

// ---------------------------------------------------------------------------
// f32 -> bf16 convert: 6 slices of 4,194,304 elems (x = slices 0,1; weights 2-5)
// ---------------------------------------------------------------------------
__global__ __launch_bounds__(256) void cvt_kernel(
    const float* __restrict__ x,  const float* __restrict__ wq,
    const float* __restrict__ wk, const float* __restrict__ wv,
    const float* __restrict__ wo,
    bf16_t* __restrict__ xb,  bf16_t* __restrict__ wqb,
    bf16_t* __restrict__ wkb, bf16_t* __restrict__ wvb,
    bf16_t* __restrict__ wob) {
  const int z = blockIdx.z;
  const float* src; bf16_t* dst; size_t off = 0;
  if      (z == 0) { src = x;  dst = xb;  off = 0; }
  else if (z == 1) { src = x;  dst = xb;  off = 4194304; }
  else if (z == 2) { src = wq; dst = wqb; }
  else if (z == 3) { src = wk; dst = wkb; }
  else if (z == 4) { src = wv; dst = wvb; }
  else             { src = wo; dst = wob; }
  const size_t i = off + ((size_t)blockIdx.x * 256 + threadIdx.x) * 8;
  *(bf16x8*)(dst + i) = ld8c(src + i);
}

// ---------------------------------------------------------------------------
// bf16 NT GEMM, async global->LDS staging (m97). C = A[M,K] * W[N,K]^T.
// 128x128 tile, BK=32, 256 threads. (used by out_gemm only now)
// ---------------------------------------------------------------------------
template <typename TC, bool TR>
__device__ __forceinline__ void gemm_async(const bf16_t* __restrict__ A,
                                           const bf16_t* __restrict__ W,
                                           TC* __restrict__ C) {
  constexpr int K  = D;
  constexpr int BK = 32;
  __shared__ __align__(16) bf16_t Ash[128 * BK];
  __shared__ __align__(16) bf16_t Bsh[128 * BK];
  const int tid = threadIdx.x;
  const int w = tid >> 6, lane = tid & 63;
  const int c = lane & 15, g = lane >> 4;
  const int wm = w >> 1, wn = w & 1;
  const int rowBase = blockIdx.y * 128;
  const int colBase = blockIdx.x * 128;

  f32x4 acc[4][4] = {};

  for (int k0 = 0; k0 < K; k0 += BK) {
    __syncthreads();
    #pragma unroll
    for (int r = 0; r < 2; ++r) {
      const int cid = r * 256 + tid;
      const int row = cid >> 2, q = cid & 3;
      async_ld16(A + (size_t)(rowBase + row) * K + k0 + q * 8,
                 Ash + r * 2048 + w * 512);
      async_ld16(W + (size_t)(colBase + row) * K + k0 + q * 8,
                 Bsh + r * 2048 + w * 512);
    }
    __syncthreads();

    bf16x8 af[4], bf[4];
    #pragma unroll
    for (int i = 0; i < 4; ++i) af[i] = ld8(Ash + (wm * 64 + i * 16 + c) * BK + g * 8);
    #pragma unroll
    for (int j = 0; j < 4; ++j) bf[j] = ld8(Bsh + (wn * 64 + j * 16 + c) * BK + g * 8);
    #pragma unroll
    for (int i = 0; i < 4; ++i)
      #pragma unroll
      for (int j = 0; j < 4; ++j)
        acc[i][j] = __builtin_amdgcn_mfma_f32_16x16x32_bf16(af[i], bf[j], acc[i][j], 0, 0, 0);
  }

  // C/D layout: col=lane&15, row=(lane>>4)*4+reg (m89/m91)
  #pragma unroll
  for (int i = 0; i < 4; ++i)
    #pragma unroll
    for (int j = 0; j < 4; ++j) {
      if (TR) {
        const int col  = colBase + wn * 64 + j * 16 + c;
        const int row0 = rowBase + wm * 64 + i * 16 + g * 4;
        bf16x4 v;
        #pragma unroll
        for (int r = 0; r < 4; ++r) v[r] = (bf16_t)acc[i][j][r];
        *(bf16x4*)((bf16_t*)C + (size_t)col * S + row0) = v;
      } else {
        #pragma unroll
        for (int r = 0; r < 4; ++r) {
          const int row = rowBase + wm * 64 + i * 16 + g * 4 + r;
          const int col = colBase + wn * 64 + j * 16 + c;
          C[(size_t)row * D + col] = (TC)acc[i][j][r];
        }
      }
    }
}

// ---------------------------------------------------------------------------
// Fused QKV GEMM: the 3 projections share A (=x). Stage the A-tile ONCE per
// K-step, stage 3 B-tiles, run 3x16 MFMA into acc[3][4][4] -> triples the
// MFMA work amortizing each barrier-pair's vmcnt drain (the m97 structural
// cost: MfmaUtil was 34% at 16 MFMA/K-step; model T=D+M -> T'=D+3M => ~1.8x).
// VGPR: acc 192 + frags ~= 230; __launch_bounds__(256,2) caps at 256 (2
// blocks/CU = 2 waves/SIMD). LDS 32 KB (Ash 8 + 3x Bsh 8). Grid 16x32 = 512
// blocks = exactly 2/CU, uniform work. V output written transposed (V^T).
// ---------------------------------------------------------------------------
__global__ __launch_bounds__(256, 2) void qkv_gemm_fused(
    const bf16_t* __restrict__ X,
    const bf16_t* __restrict__ Wq, const bf16_t* __restrict__ Wk,
    const bf16_t* __restrict__ Wv,
    bf16_t* __restrict__ Qo, bf16_t* __restrict__ Ko, bf16_t* __restrict__ VTo) {
  constexpr int K  = D;
  constexpr int BK = 32;
  __shared__ __align__(16) bf16_t Ash[128 * BK];
  __shared__ __align__(16) bf16_t Bsh[3][128 * BK];
  const int tid = threadIdx.x;
  const int w = tid >> 6, lane = tid & 63;
  const int c = lane & 15, g = lane >> 4;
  const int wm = w >> 1, wn = w & 1;
  const int rowBase = blockIdx.y * 128;
  const int colBase = blockIdx.x * 128;

  f32x4 acc[3][4][4] = {};

  for (int k0 = 0; k0 < K; k0 += BK) {
    __syncthreads();
    #pragma unroll
    for (int r = 0; r < 2; ++r) {
      const int cid = r * 256 + tid;
      const int row = cid >> 2, q = cid & 3;
      const size_t aoff = (size_t)(rowBase + row) * K + k0 + q * 8;
      const size_t boff = (size_t)(colBase + row) * K + k0 + q * 8;
      async_ld16(X  + aoff, Ash    + r * 2048 + w * 512);
      async_ld16(Wq + boff, Bsh[0] + r * 2048 + w * 512);
      async_ld16(Wk + boff, Bsh[1] + r * 2048 + w * 512);
      async_ld16(Wv + boff, Bsh[2] + r * 2048 + w * 512);
    }
    __syncthreads();

    bf16x8 af[4];
    #pragma unroll
    for (int i = 0; i < 4; ++i) af[i] = ld8(Ash + (wm * 64 + i * 16 + c) * BK + g * 8);
    #pragma unroll
    for (int m = 0; m < 3; ++m) {
      bf16x8 bf[4];
      #pragma unroll
      for (int j = 0; j < 4; ++j) bf[j] = ld8(Bsh[m] + (wn * 64 + j * 16 + c) * BK + g * 8);
      #pragma unroll
      for (int i = 0; i < 4; ++i)
        #pragma unroll
        for (int j = 0; j < 4; ++j)
          acc[m][i][j] = __builtin_amdgcn_mfma_f32_16x16x32_bf16(af[i], bf[j], acc[m][i][j], 0, 0, 0);
    }
  }

  // epilogue: Q, K row-major; V transposed ([N][S] = V^T)
  #pragma unroll
  for (int i = 0; i < 4; ++i)
    #pragma unroll
    for (int j = 0; j < 4; ++j) {
      #pragma unroll
      for (int r = 0; r < 4; ++r) {
        const int row = rowBase + wm * 64 + i * 16 + g * 4 + r;
        const int col = colBase + wn * 64 + j * 16 + c;
        Qo[(size_t)row * D + col] = (bf16_t)acc[0][i][j][r];
        Ko[(size_t)row * D + col] = (bf16_t)acc[1][i][j][r];
      }
      const int colv  = colBase + wn * 64 + j * 16 + c;
      const int row0v = rowBase + wm * 64 + i * 16 + g * 4;
      bf16x4 v;
      #pragma unroll
      for (int r = 0; r < 4; ++r) v[r] = (bf16_t)acc[2][i][j][r];
      *(bf16x4*)(VTo + (size_t)colv * S + row0v) = v;
    }
}

__global__ __launch_bounds__(256) void out_gemm_bf16(
    const bf16_t* __restrict__ A, const bf16_t* __restrict__ W,
    float* __restrict__ C) {
  gemm_async<float, false>(A, W, C);
}

// ---------------------------------------------------------------------------
// Causal flash attention — EXACT round-8 kernel (best measured: attn ~129us,
// total 431.5). 512 threads = 8 waves, work stealing, 32-row waves; item_s
// folded into the smem tail so the LDS request is exactly 81920 B -> 2
// blocks/CU. Swapped QK^T; P via per-wave LDS (b64 writes, b128 reads,
// pair-preserving swizzle); fixed softmax shift m=0; global_load_lds
// double-buffer, ONE __syncthreads per tile; source-chunk XOR swizzle.
//   KB[2][64 keys][128 dh]   16 KB x2
//   VB[2][128 dh][64 keys]   16 KB x2
//   Psh[8 waves][2 i][16 q][32 k]  16 KB   (item_s in last 4 B)
// ---------------------------------------------------------------------------
__global__ __launch_bounds__(512, 2) void attn_kernel(
    const bf16_t* __restrict__ Q, const bf16_t* __restrict__ Kb,
    const bf16_t* __restrict__ VTg, bf16_t* __restrict__ O,
    const int* __restrict__ causal_p, int* __restrict__ ctr) {
  __shared__ __align__(16) bf16_t smem[40960];       // exactly 80 KB
  bf16_t* const KB0 = smem;                          // [2][8192]
  bf16_t* const VB0 = smem + 16384;                  // [2][8192]
  bf16_t* const Psh = smem + 32768;                  // [8][1024]
  int* const item_sp = (int*)(smem + 40958);         // aliases P tail (safe)

  const int tid = threadIdx.x, w = tid >> 6, lane = tid & 63;
  const int c = lane & 15, g = lane >> 4;
  const int wq = w >> 1, wk = w & 1;
  const int causal = causal_p[0];
  constexpr float QS = 0.08838834764831845f * 1.4426950408889634f; // sm*log2e

  // staging coords: cid = r*512+tid enumerates 16B chunks of a 16KB tile.
  // K tile [kn 64][dh 128]: row=cid>>4, chunk=cid&15 ; source chunk ^= row&7.
  // V tile [d 128][key 64]: row=cid>>3, chunk=cid&7  ; source chunk ^= row&7.
  int knA[2], qK8[2], dVA[2], qV8[2];
  #pragma unroll
  for (int r = 0; r < 2; ++r) {
    const int cid = r * 512 + tid;
    knA[r] = cid >> 4; qK8[r] = (((cid & 15) ^ (knA[r] & 7)) << 3);
    dVA[r] = cid >> 3; qV8[r] = (((cid & 7) ^ (dVA[r] & 7)) << 3);
  }

  bf16_t* const Pw = Psh + w * 1024;    // [2 i][16 q-rows][32 keys]
  const int psw = (c >> 1) & 3;         // P pair-swizzle term for this lane

  while (true) {
    if (tid == 0) *item_sp = atomicAdd(ctr, 1);
    __syncthreads();                    // publish item_s; prev epilogue done
    const int it = *item_sp;
    if (it >= 512) break;
    const int t = causal ? (31 - (it >> 4)) : (it >> 4);     // heavy-first
    const int h = it & 15;
    const int qrow0 = t * 128 + wq * 32;
    const int ktiles = causal ? (2 * t + 2) : (S / 64);

    // incremental staging source pointers (advance by fixed strides/tile)
    const bf16_t* kSrc[2];
    const bf16_t* vSrc[2];
    #pragma unroll
    for (int r = 0; r < 2; ++r) {
      kSrc[r] = Kb + (size_t)knA[r] * D + h * DH + qK8[r];
      vSrc[r] = VTg + (size_t)(h * DH + dVA[r]) * S + qV8[r];
    }
    // prologue: stage tile 0 into buffer 0 (flies under Q-frag loads below)
    #pragma unroll
    for (int r = 0; r < 2; ++r) {
      async_ld16(kSrc[r], KB0 + r * 4096 + w * 512);
      async_ld16(vSrc[r], VB0 + r * 4096 + w * 512);
      kSrc[r] += (size_t)64 * D;
      vSrc[r] += 64;
    }

    // Q fragments (B operand: n=lane&15=q-row in i-group, k=(lane>>4)*8+j)
    bf16x8 qf[2][4];
    #pragma unroll
    for (int i = 0; i < 2; ++i)
      #pragma unroll
      for (int kf = 0; kf < 4; ++kf) {
        const bf16x8 raw = ld8(Q + (size_t)(qrow0 + i * 16 + c) * D + h * DH + kf * 32 + g * 8);
        bf16x8 sc;
        #pragma unroll
        for (int e = 0; e < 8; ++e) sc[e] = (bf16_t)((float)raw[e] * QS);
        qf[i][kf] = sc;
      }

    f32x4 o_acc[2][8] = {};
    float psum[2] = {0.0f, 0.0f};

    __syncthreads();   // tile 0 landed (vmcnt(0) drained at barrier)

    int cur = 0;
    for (int kt = 0; kt < ktiles; ++kt) {
      // issue next tile's loads into alt buffer (fly during compute)
      if (kt + 1 < ktiles) {
        const int alt = cur ^ 1;
        #pragma unroll
        for (int r = 0; r < 2; ++r) {
          async_ld16(kSrc[r], KB0 + alt * 8192 + r * 4096 + w * 512);
          async_ld16(vSrc[r], VB0 + alt * 8192 + r * 4096 + w * 512);
          kSrc[r] += (size_t)64 * D;
          vSrc[r] += 64;
        }
      }

      const bf16_t* const KB = KB0 + cur * 8192;
      const bf16_t* const VB = VB0 + cur * 8192;
      const int kb = kt * 64 + wk * 32;          // this wave's key base

      // fully-masked key-half for this wave's 32 rows?
      const bool active = !causal || (kb <= qrow0 + 31);
      if (active) {
        __builtin_amdgcn_s_setprio(1);
        // --- S^T = K Q^T (swapped): per slab nf, per q-group i ---
        #pragma unroll
        for (int nf = 0; nf < 2; ++nf) {
          const int rr = wk * 32 + nf * 16 + c;   // key row in tile (A m-idx)
          bf16x8 kk[4];
          #pragma unroll
          for (int kf = 0; kf < 4; ++kf)
            kk[kf] = ld8(KB + rr * 128 + ((((kf << 2) + g) ^ (rr & 7)) << 3));
          #pragma unroll
          for (int i = 0; i < 2; ++i) {
            f32x4 s = {};
            #pragma unroll
            for (int kf = 0; kf < 4; ++kf)
              s = __builtin_amdgcn_mfma_f32_16x16x32_bf16(kk[kf], qf[i][kf], s, 0, 0, 0);
            // causal mask: key = kb+nf*16+g*4+r, qrow = qrow0+i*16+c
            if (causal && (kb + nf * 16 + 15 > qrow0 + i * 16)) {
              #pragma unroll
              for (int r_ = 0; r_ < 4; ++r_)
                if (kb + nf * 16 + g * 4 + r_ > qrow0 + i * 16 + c) s[r_] = -1e30f;
            }
            // P = exp2(S) (fixed m=0); pack 4 keys -> one ds_write_b64
            bf16x4 pq;
            #pragma unroll
            for (int r_ = 0; r_ < 4; ++r_) {
              const float pv = exp2f(s[r_]);
              psum[i] += pv;
              pq[r_] = (bf16_t)pv;
            }
            // chunk p = key 8-group (nf*2 + g>>1), swizzled per lane pair
            const int p  = (nf << 1) | (g >> 1);
            const int pp = ((p ^ psw) << 1) | (g & 1);
            *(bf16x4*)(Pw + i * 512 + c * 32 + pp * 4) = pq;
          }
        }

        // --- O += P V  (same-wave LDS write->read, ordered) ---
        bf16x8 pf[2];
        #pragma unroll
        for (int i = 0; i < 2; ++i)
          pf[i] = ld8(Pw + i * 512 + c * 32 + ((g ^ psw) << 3));
        #pragma unroll
        for (int nf = 0; nf < 8; ++nf) {
          const int dl = nf * 16 + c;
          const bf16x8 vf = ld8(VB + dl * 64 + ((((wk << 2) + g) ^ (dl & 7)) << 3));
          o_acc[0][nf] = __builtin_amdgcn_mfma_f32_16x16x32_bf16(pf[0], vf, o_acc[0][nf], 0, 0, 0);
          o_acc[1][nf] = __builtin_amdgcn_mfma_f32_16x16x32_bf16(pf[1], vf, o_acc[1][nf], 0, 0, 0);
        }
        __builtin_amdgcn_s_setprio(0);
      }

      __syncthreads();   // next tile staged; prev reads done; swap
      cur ^= 1;
    }

    // --- merge wk=1 -> wk=0 via LDS scratch (4 wq x 64 lanes x 72 f32 =
    //     72 KB; tops at byte 73728 < 81916 (item_s); loop-final barrier
    //     ordered the buffer reuse) ---
    float* const slot = (float*)smem + (size_t)(wq * 64 + lane) * 72;
    if (wk == 1) {
      #pragma unroll
      for (int i = 0; i < 2; ++i)
        #pragma unroll
        for (int nf = 0; nf < 8; ++nf)
          *(f32x4*)(slot + (i * 8 + nf) * 4) = o_acc[i][nf];
      slot[64] = psum[0];
      slot[65] = psum[1];
    }
    __syncthreads();
    if (wk == 0) {
      #pragma unroll
      for (int i = 0; i < 2; ++i)
        #pragma unroll
        for (int nf = 0; nf < 8; ++nf)
          o_acc[i][nf] += *(const f32x4*)(slot + (i * 8 + nf) * 4);
      psum[0] += slot[64];
      psum[1] += slot[65];
      // row-sum: psum[i] is per (q-row c, g) partial; reduce over g-groups
      #pragma unroll
      for (int i = 0; i < 2; ++i) {
        float v = psum[i];
        v += __shfl_xor(v, 16); v += __shfl_xor(v, 32);
        // normalize + write: o_acc[i][nf][r] is row qrow0+i*16+g*4+r, col nf*16+c
        #pragma unroll
        for (int r_ = 0; r_ < 4; ++r_) {
          const float inv = 1.0f / __shfl(v, g * 4 + r_, 64);
          const int row = qrow0 + i * 16 + g * 4 + r_;
          #pragma unroll
          for (int nf = 0; nf < 8; ++nf)
            O[(size_t)row * D + h * DH + nf * 16 + c] = (bf16_t)(o_acc[i][nf][r_] * inv);
        }
      }
    }
  }
}

// ---------------------------------------------------------------------------
extern "C" void kernel_launch(void* const* d_in, const int* in_sizes, int n_in,
                              void* d_out, int out_size, void* d_ws, size_t ws_size,
                              hipStream_t stream) {
  const float* x  = (const float*)d_in[0];
  const float* wq = (const float*)d_in[1];
  const float* wk = (const float*)d_in[2];
  const float* wv = (const float*)d_in[3];
  const float* wo = (const float*)d_in[4];
  const int* causal = (const int*)d_in[5];
  float* out = (float*)d_out;

  bf16_t* Qb  = (bf16_t*)d_ws;           // [S][D]
  bf16_t* Kb  = Qb + (size_t)S * D;      // [S][D]
  bf16_t* VTb = Kb + (size_t)S * D;      // V^T: [D][S]
  bf16_t* Ob  = VTb + (size_t)S * D;     // [S][D]
  bf16_t* xb  = Ob + (size_t)S * D;
  bf16_t* wqb = xb + (size_t)S * D;
  bf16_t* wkb = wqb + (size_t)D * D;
  bf16_t* wvb = wkb + (size_t)D * D;
  bf16_t* wob = wvb + (size_t)D * D;
  int*    ctr = (int*)(wob + (size_t)D * D);

  // zero the attention work-queue counter (graph-capturable async memset)
  hipMemsetAsync(ctr, 0, sizeof(int), stream);

  dim3 blk(256);
  cvt_kernel<<<dim3(2048, 1, 6), blk, 0, stream>>>(x, wq, wk, wv, wo,
                                                   xb, wqb, wkb, wvb, wob);
  qkv_gemm_fused<<<dim3(D / 128, S / 128), blk, 0, stream>>>(xb, wqb, wkb, wvb,
                                                             Qb, Kb, VTb);
  attn_kernel<<<dim3(384), dim3(512), 0, stream>>>(Qb, Kb, VTb, Ob, causal, ctr);
  out_gemm_bf16<<<dim3(D / 128, S / 128), blk, 0, stream>>>(Ob, wob, out);
}